// Round 4
// baseline (1053.259 us; speedup 1.0000x reference)
//
#include <hip/hip_runtime.h>
#include <math.h>

using u16 = unsigned short;
using bf16x8 = __attribute__((ext_vector_type(8))) short;
using f32x4  = __attribute__((ext_vector_type(4))) float;

#define DEV static __device__ __forceinline__

DEV u16 f2bf(float f) {
  union { float f; unsigned u; } v; v.f = f;
  unsigned u = v.u + 0x7fffu + ((v.u >> 16) & 1u);
  return (u16)(u >> 16);
}

DEV void gload16(const void* g, void* l) {
  __builtin_amdgcn_global_load_lds(
      (const __attribute__((address_space(1))) void*)g,
      (__attribute__((address_space(3))) void*)l, 16, 0, 0);
}

// ---------------- prep kernels ----------------
__global__ void k_conv_bf16(const float* __restrict__ in, u16* __restrict__ out, int n) {
  int i = blockIdx.x * 256 + threadIdx.x;
  if (i < n) out[i] = f2bf(in[i]);
}

// in: f32 [K][Nin] row-major ; out: bf16 [Nout][K] (n-major).
// pack==1: n' = d2*48+j maps to n = d2*47+j for j<47, j==47 -> 0 (pad).
__global__ void k_transconv(const float* __restrict__ in, u16* __restrict__ out,
                            int K, int Nin, int Nout, int pack) {
  __shared__ float t[32][33];
  int kb = blockIdx.x * 32, nb = blockIdx.y * 32;
  int tx = threadIdx.x & 31, ty = threadIdx.x >> 5;  // 32 x 8
  #pragma unroll
  for (int i = 0; i < 4; ++i) {
    int k = kb + ty + i * 8;
    int no = nb + tx;
    float v = 0.f;
    if (k < K && no < Nout) {
      if (pack) {
        int r = no % 48;
        if (r < 47) v = in[(size_t)k * Nin + (no / 48) * 47 + r];
      } else {
        v = in[(size_t)k * Nin + no];
      }
    }
    t[ty + i * 8][tx] = v;
  }
  __syncthreads();
  #pragma unroll
  for (int i = 0; i < 4; ++i) {
    int no = nb + ty + i * 8;
    int k = kb + tx;
    if (no < Nout && k < K) out[(size_t)no * K + k] = f2bf(t[tx][ty + i * 8]);
  }
}

// ---------------- GEMM + ReLU (BM=128,BN=128,BK=32, 4 waves) for GEMM1/2 ----------------
__global__ __launch_bounds__(256)
void k_gemm_relu(const u16* __restrict__ A, const u16* __restrict__ Bt,
                 const float* __restrict__ bias, u16* __restrict__ C,
                 int N, int K) {
  constexpr int BM = 128, BN = 128, BK = 32;
  __shared__ __align__(16) u16 lds[(BM + BN) * BK];
  int tid = threadIdx.x, w = tid >> 6, lane = tid & 63;
  int bn = blockIdx.x, bm = blockIdx.y;
  int brow = bm * BM, bcol = bn * BN;
  int wm = w >> 1, wn = w & 1;
  int fr = lane & 15, fg = lane >> 4;
  f32x4 acc[4][4];
  #pragma unroll
  for (int i = 0; i < 4; ++i)
    #pragma unroll
    for (int j = 0; j < 4; ++j) acc[i][j] = (f32x4){0.f, 0.f, 0.f, 0.f};

  constexpr int ACH = BM * BK / 8;
  constexpr int CALLS = (BM + BN) * BK / 8 / 64;

  for (int kt = 0; kt < K; kt += BK) {
    for (int j = 0; j * 4 + w < CALLS; ++j) {
      int cb = (j * 4 + w) * 64;
      int c = cb + lane;
      const u16* g;
      if (c < ACH) {
        int row = c >> 2, c8 = c & 3;
        g = A + (size_t)(brow + row) * K + kt + c8 * 8;
      } else {
        int b = c - ACH;
        int nn = b >> 2, c8 = b & 3;
        g = Bt + (size_t)(bcol + nn) * K + kt + c8 * 8;
      }
      gload16(g, &lds[cb * 8]);
    }
    asm volatile("s_waitcnt vmcnt(0)" ::: "memory");
    __syncthreads();

    const u16* Al = lds;
    const u16* Bl = lds + BM * BK;
    bf16x8 af[4], bfr[4];
    #pragma unroll
    for (int mi = 0; mi < 4; ++mi)
      af[mi] = *(const bf16x8*)&Al[(wm * 64 + mi * 16 + fr) * BK + fg * 8];
    #pragma unroll
    for (int ni = 0; ni < 4; ++ni)
      bfr[ni] = *(const bf16x8*)&Bl[(wn * 64 + ni * 16 + fr) * BK + fg * 8];
    #pragma unroll
    for (int mi = 0; mi < 4; ++mi)
      #pragma unroll
      for (int ni = 0; ni < 4; ++ni)
        acc[mi][ni] = __builtin_amdgcn_mfma_f32_16x16x32_bf16(af[mi], bfr[ni], acc[mi][ni], 0, 0, 0);
    __syncthreads();
  }

  #pragma unroll
  for (int ni = 0; ni < 4; ++ni) {
    int col = bcol + wn * 64 + ni * 16 + fr;
    float bb = bias[col];
    #pragma unroll
    for (int mi = 0; mi < 4; ++mi) {
      #pragma unroll
      for (int q = 0; q < 4; ++q) {
        int row = brow + wm * 64 + mi * 16 + fg * 4 + q;
        float vv = acc[mi][ni][q] + bb;
        C[(size_t)row * N + col] = f2bf(vv > 0.f ? vv : 0.f);
      }
    }
  }
}

// ------- GEMM3 fused with spline: BM=256, BN=192, BK=64, 8 waves -------
// m201-faithful schedule: 4 phases/K-tile, TWO barriers per phase, all 7 stage
// units for tile t+1 issued at ph0 of tile t (4-6 phase lead), counted vmcnt:
//   end-ph1: vmcnt(7)  guards A1,A3 of tile t   (issued 5 phases earlier)
//   end-ph3: vmcnt(2)  guards B*,A0,A2 of t+1   (issued 4 phases earlier)
// Units (8KB, 1 gload16/thread): A0=rows0-63, A1=64-127, A2=128-191, A3=192-255,
// B0..B2=rows 0-191. wm0 waves use A0/A1, wm1 use A2/A3; issue order
// B0,B1,B2,A0,A2,A1,A3 so the vmcnt positions match deadlines for both wm.
__global__ __launch_bounds__(512, 2)
void k_gemm3_fused(const u16* __restrict__ A, const u16* __restrict__ Bt,
                   const float* __restrict__ b2, const float* __restrict__ x2,
                   float* __restrict__ y2, float* __restrict__ ldpart) {
  extern __shared__ char smem[];
  const int tid = threadIdx.x, w = tid >> 6, lane = tid & 63;
  const int wm = w >> 2, wn = w & 3;
  const int fr = lane & 15, fg = lane >> 4;

  int bid = blockIdx.x;
  int swz = (bid & 7) * 512 + (bid >> 3);
  const int bm = swz >> 6, bn = swz & 63;
  const int brow = bm * 256;

  // staging: unit chunk c: row_local = tid>>3, c8 = tid&7; source pre-swizzled
  const int csrc = (tid & 7) ^ ((tid >> 3) & 7);
  const u16* gA[4]; const u16* gB[3];
  int ldsA[4], ldsB[3];
  #pragma unroll
  for (int u = 0; u < 4; ++u) {
    gA[u] = A + (size_t)(brow + u * 64 + (tid >> 3)) * 1024 + csrc * 8;
    ldsA[u] = u * 8192 + tid * 16;
  }
  #pragma unroll
  for (int u = 0; u < 3; ++u) {
    gB[u] = Bt + (size_t)(bn * 192 + u * 64 + (tid >> 3)) * 1024 + csrc * 8;
    ldsB[u] = 65536 + u * 8192 + tid * 16;
  }

  // issue all 7 units of tile t1 (order: B0,B1,B2,A0,A2,A1,A3)
#define ISSUE_ALL(t1) {                                              \
    const size_t ko_ = (size_t)(t1) * 64;                            \
    const int poA_ = ((t1) & 1) * 32768, poB_ = ((t1) & 1) * 24576;  \
    gload16(gB[0] + ko_, smem + ldsB[0] + poB_);                     \
    gload16(gB[1] + ko_, smem + ldsB[1] + poB_);                     \
    gload16(gB[2] + ko_, smem + ldsB[2] + poB_);                     \
    gload16(gA[0] + ko_, smem + ldsA[0] + poA_);                     \
    gload16(gA[2] + ko_, smem + ldsA[2] + poA_);                     \
    gload16(gA[1] + ko_, smem + ldsA[1] + poA_);                     \
    gload16(gA[3] + ko_, smem + ldsA[3] + poA_); }

#define BAR_IN() { __builtin_amdgcn_s_barrier();                     \
    asm volatile("s_waitcnt lgkmcnt(0)" ::: "memory");               \
    __builtin_amdgcn_sched_barrier(0); }
#define BAR_OUT() { __builtin_amdgcn_s_barrier(); }
#define VM_WAIT(n) { __builtin_amdgcn_sched_barrier(0);              \
    asm volatile("s_waitcnt vmcnt(" #n ")" ::: "memory");            \
    __builtin_amdgcn_sched_barrier(0); }

  // swizzled read chunk offsets (bytes): chunk = (kk*4+fg) ^ (row&7), row&7 == fr&7
  const int sc0 = ((fg ^ (fr & 7)) << 4);
  const int sc1 = (((4 + fg) ^ (fr & 7)) << 4);

#define RD_A(dst, mh, scv) {                                          \
    const char* ap_ = Ab + (wm * 128 + (mh) * 64 + fr) * 128 + (scv); \
    dst[0] = *(const bf16x8*)(ap_);                                   \
    dst[1] = *(const bf16x8*)(ap_ + 2048);                            \
    dst[2] = *(const bf16x8*)(ap_ + 4096);                            \
    dst[3] = *(const bf16x8*)(ap_ + 6144); }
#define RD_B(dst, scv) {                                              \
    const char* bp_ = Bb + (wn * 48 + fr) * 128 + (scv);              \
    dst[0] = *(const bf16x8*)(bp_);                                   \
    dst[1] = *(const bf16x8*)(bp_ + 2048);                            \
    dst[2] = *(const bf16x8*)(bp_ + 4096); }
#define MM(mh, af, bf) {                                              \
    __builtin_amdgcn_s_setprio(1);                                    \
    _Pragma("unroll")                                                 \
    for (int i_ = 0; i_ < 4; ++i_)                                    \
      _Pragma("unroll")                                               \
      for (int n_ = 0; n_ < 3; ++n_)                                  \
        acc[(mh) * 4 + i_][n_] = __builtin_amdgcn_mfma_f32_16x16x32_bf16(af[i_], bf[n_], acc[(mh) * 4 + i_][n_], 0, 0, 0); \
    __builtin_amdgcn_s_setprio(0); }

  f32x4 acc[8][3];
  #pragma unroll
  for (int m = 0; m < 8; ++m)
    #pragma unroll
    for (int n = 0; n < 3; ++n) acc[m][n] = (f32x4){0.f, 0.f, 0.f, 0.f};

  // prologue: stage tile 0; A1,A3 may stay in flight past the barrier
  ISSUE_ALL(0);
  VM_WAIT(2);
  __builtin_amdgcn_s_barrier();

  for (int t = 0; t < 15; ++t) {
    const int p = t & 1;
    const char* Ab = smem + p * 32768;
    const char* Bb = smem + 65536 + p * 24576;
    bf16x8 a[4], b0[3], b1[3];
    // ---- ph0: (mh0, kk0) ----
    ISSUE_ALL(t + 1);
    RD_B(b0, sc0);
    RD_A(a, 0, sc0);
    BAR_IN();
    MM(0, a, b0);
    BAR_OUT();
    // ---- ph1: (mh0, kk1) ----
    RD_B(b1, sc1);
    RD_A(a, 0, sc1);
    BAR_IN();
    MM(0, a, b1);
    VM_WAIT(7);           // A1,A3 of tile t landed (for ph2/ph3 reads after barrier)
    BAR_OUT();
    // ---- ph2: (mh1, kk0) ----
    RD_A(a, 1, sc0);
    BAR_IN();
    MM(1, a, b0);
    BAR_OUT();
    // ---- ph3: (mh1, kk1) ----
    RD_A(a, 1, sc1);
    BAR_IN();
    MM(1, a, b1);
    VM_WAIT(2);           // B*,A0,A2 of tile t+1 landed (for ph0 reads after barrier)
    BAR_OUT();
  }
  // ---- peeled tile 15 (parity 1) ----
  {
    const char* Ab = smem + 32768;
    const char* Bb = smem + 65536 + 24576;
    bf16x8 a[4], b0[3], b1[3];
    RD_B(b0, sc0);
    RD_A(a, 0, sc0);
    BAR_IN();
    MM(0, a, b0);
    BAR_OUT();
    RD_B(b1, sc1);
    RD_A(a, 0, sc1);
    BAR_IN();
    MM(0, a, b1);
    VM_WAIT(0);
    BAR_OUT();
    RD_A(a, 1, sc0);
    BAR_IN();
    MM(1, a, b0);
    BAR_OUT();
    RD_A(a, 1, sc1);
    BAR_IN();
    MM(1, a, b1);
  }
  __syncthreads();

  // ---- epilogue: per-wave 128x48 p-subtile -> LDS slot -> spline (2 wm-rounds) ----
  float* ldaccs = (float*)(smem + 100352);  // [256][4]
  float* slot = (float*)smem + wn * (128 * 49);
  const int d2 = bn * 4 + wn;
  const float* bb = b2 + (size_t)d2 * 47;

  #pragma unroll
  for (int round = 0; round < 2; ++round) {
    if (wm == round) {
      #pragma unroll
      for (int m = 0; m < 8; ++m)
        #pragma unroll
        for (int n = 0; n < 3; ++n)
          #pragma unroll
          for (int q = 0; q < 4; ++q)
            slot[(m * 16 + fg * 4 + q) * 49 + n * 16 + fr] = acc[m][n][q];
      asm volatile("s_waitcnt lgkmcnt(0)" ::: "memory");
      #pragma unroll
      for (int rr = 0; rr < 2; ++rr) {
        int lr = rr * 64 + lane;
        int grow = brow + wm * 128 + lr;
        const float* pr = slot + lr * 49;

        float wv[16], hv[16];
        #pragma unroll
        for (int j = 0; j < 16; ++j) wv[j] = pr[j] + bb[j];
        #pragma unroll
        for (int j = 0; j < 16; ++j) hv[j] = pr[16 + j] + bb[16 + j];

        float x = x2[(size_t)grow * 256 + d2];
        float xc = fminf(fmaxf(x, -3.f), 3.f);

        float mw = wv[0];
        #pragma unroll
        for (int j = 1; j < 16; ++j) mw = fmaxf(mw, wv[j]);
        float sw = 0.f;
        #pragma unroll
        for (int j = 0; j < 16; ++j) { wv[j] = __expf(wv[j] - mw); sw += wv[j]; }
        float scw = 0.984f / sw;

        float mh = hv[0];
        #pragma unroll
        for (int j = 1; j < 16; ++j) mh = fmaxf(mh, hv[j]);
        float sh = 0.f;
        #pragma unroll
        for (int j = 0; j < 16; ++j) { hv[j] = __expf(hv[j] - mh); sh += hv[j]; }
        float sch = 0.984f / sh;

        int idx = 0;
        float xk = -3.f, cum = 0.f;
        #pragma unroll
        for (int i = 1; i <= 15; ++i) {
          cum += 0.001f + wv[i - 1] * scw;
          float cwi = 6.f * cum - 3.f;
          if (xc >= cwi) { idx = i; xk = cwi; }
        }
        float yk = -3.f, cumh = 0.f;
        #pragma unroll
        for (int i = 1; i <= 15; ++i) {
          cumh += 0.001f + hv[i - 1] * sch;
          float chi = 6.f * cumh - 3.f;
          if (i == idx) yk = chi;
        }
        float wk = 1.f, hk = 1.f;
        #pragma unroll
        for (int i = 0; i < 16; ++i) {
          if (i == idx) {
            wk = 6.f * (0.001f + wv[i] * scw);
            hk = 6.f * (0.001f + hv[i] * sch);
          }
        }
        float dk = 1.f, dk1 = 1.f;
        #pragma unroll
        for (int i = 1; i <= 15; ++i) {
          float u = pr[32 + i - 1] + bb[32 + i - 1];
          float e = __expf(u);
          float dd = 0.001f + (u > 15.f ? u : log1pf(e));
          if (i == idx) dk = dd;
          if (i == idx + 1) dk1 = dd;
        }

        float sk = hk / wk;
        float th = (xc - xk) / wk;
        float om = 1.f - th;
        float t1m = th * om;
        float den = sk + (dk + dk1 - 2.f * sk) * t1m;
        float y = yk + hk * (sk * th * th + dk * t1m) / den;
        float deriv = sk * sk * (dk1 * th * th + 2.f * sk * t1m + dk * om * om) / (den * den);
        bool inside = (x > -3.f) && (x < 3.f);
        float yout = inside ? y : x;
        float ld = inside ? __logf(deriv) : 0.f;

        y2[(size_t)grow * 256 + d2] = yout;
        ldaccs[(wm * 128 + lr) * 4 + wn] = ld;
      }
    }
    __syncthreads();
  }

  if (tid < 256) {
    int row = tid;
    float s = ldaccs[row * 4] + ldaccs[row * 4 + 1] + ldaccs[row * 4 + 2] + ldaccs[row * 4 + 3];
    ldpart[(size_t)bn * 16384 + brow + row] = s;
  }
}

__global__ void k_reduce_ld(const float* __restrict__ part, float* __restrict__ out) {
  int r = blockIdx.x * 256 + threadIdx.x;
  float s = 0.f;
  for (int j = 0; j < 64; ++j) s += part[(size_t)j * 16384 + r];
  out[r] = s;
}

// ---------------- launch ----------------
extern "C" void kernel_launch(void* const* d_in, const int* in_sizes, int n_in,
                              void* d_out, int out_size, void* d_ws, size_t ws_size,
                              hipStream_t stream) {
  const float* x1 = (const float*)d_in[0];
  const float* x2 = (const float*)d_in[1];
  const float* W0 = (const float*)d_in[2];
  const float* b0 = (const float*)d_in[3];
  const float* W1 = (const float*)d_in[4];
  const float* b1 = (const float*)d_in[5];
  const float* W2 = (const float*)d_in[6];
  const float* b2 = (const float*)d_in[7];
  float* y2 = (float*)d_out;
  float* logdet = y2 + (size_t)16384 * 256;

  char* ws = (char*)d_ws;
  u16* W2t = (u16*)ws;                                   // 25165824
  u16* W0t = (u16*)(ws + 25165824);                      //   524288
  u16* W1t = (u16*)(ws + 25165824 + 524288);             //  2097152
  u16* x1b = (u16*)(ws + 27787264);                      //  8388608
  float* ldp = (float*)(ws + 27787264);                  // aliases x1b (dead by GEMM3); 64*16384*4=4MB
  u16* h1  = (u16*)(ws + 36175872);                      // 33554432
  u16* h2  = (u16*)(ws + 69730304);                      // 33554432

  hipFuncSetAttribute((const void*)k_gemm3_fused,
                      hipFuncAttributeMaxDynamicSharedMemorySize, 114688);

  k_conv_bf16<<<16384, 256, 0, stream>>>(x1, x1b, 16384 * 256);
  k_transconv<<<dim3(8, 32), 256, 0, stream>>>(W0, W0t, 256, 1024, 1024, 0);
  k_transconv<<<dim3(32, 32), 256, 0, stream>>>(W1, W1t, 1024, 1024, 1024, 0);
  k_transconv<<<dim3(32, 384), 256, 0, stream>>>(W2, W2t, 1024, 12032, 12288, 1);

  k_gemm_relu<<<dim3(8, 128), 256, 0, stream>>>(x1b, W0t, b0, h1, 1024, 256);
  k_gemm_relu<<<dim3(8, 128), 256, 0, stream>>>(h1, W1t, b1, h2, 1024, 1024);
  k_gemm3_fused<<<4096, 512, 114688, stream>>>(h2, W2t, b2, x2, y2, ldp);
  k_reduce_ld<<<64, 256, 0, stream>>>(ldp, logdet);
}

// Round 5
// 865.709 us; speedup vs baseline: 1.2166x; 1.2166x over previous
//
#include <hip/hip_runtime.h>
#include <math.h>

using u16 = unsigned short;
using bf16x8 = __attribute__((ext_vector_type(8))) short;
using f32x4  = __attribute__((ext_vector_type(4))) float;

#define DEV static __device__ __forceinline__

DEV u16 f2bf(float f) {
  union { float f; unsigned u; } v; v.f = f;
  unsigned u = v.u + 0x7fffu + ((v.u >> 16) & 1u);
  return (u16)(u >> 16);
}

DEV void gload16(const void* g, void* l) {
  __builtin_amdgcn_global_load_lds(
      (const __attribute__((address_space(1))) void*)g,
      (__attribute__((address_space(3))) void*)l, 16, 0, 0);
}

// ---------------- prep kernels ----------------
__global__ void k_conv_bf16(const float* __restrict__ in, u16* __restrict__ out, int n) {
  int i = blockIdx.x * 256 + threadIdx.x;
  if (i < n) out[i] = f2bf(in[i]);
}

// in: f32 [K][Nin] row-major ; out: bf16 [Nout][K] (n-major).
// pack==1: n' = d2*48+j maps to n = d2*47+j for j<47, j==47 -> 0 (pad).
__global__ void k_transconv(const float* __restrict__ in, u16* __restrict__ out,
                            int K, int Nin, int Nout, int pack) {
  __shared__ float t[32][33];
  int kb = blockIdx.x * 32, nb = blockIdx.y * 32;
  int tx = threadIdx.x & 31, ty = threadIdx.x >> 5;  // 32 x 8
  #pragma unroll
  for (int i = 0; i < 4; ++i) {
    int k = kb + ty + i * 8;
    int no = nb + tx;
    float v = 0.f;
    if (k < K && no < Nout) {
      if (pack) {
        int r = no % 48;
        if (r < 47) v = in[(size_t)k * Nin + (no / 48) * 47 + r];
      } else {
        v = in[(size_t)k * Nin + no];
      }
    }
    t[ty + i * 8][tx] = v;
  }
  __syncthreads();
  #pragma unroll
  for (int i = 0; i < 4; ++i) {
    int no = nb + ty + i * 8;
    int k = kb + tx;
    if (no < Nout && k < K) out[(size_t)no * K + k] = f2bf(t[tx][ty + i * 8]);
  }
}

// ---------------- GEMM + ReLU (BM=128,BN=128,BK=32, 4 waves) for GEMM1/2 ----------------
__global__ __launch_bounds__(256)
void k_gemm_relu(const u16* __restrict__ A, const u16* __restrict__ Bt,
                 const float* __restrict__ bias, u16* __restrict__ C,
                 int N, int K) {
  constexpr int BM = 128, BN = 128, BK = 32;
  __shared__ __align__(16) u16 lds[(BM + BN) * BK];
  int tid = threadIdx.x, w = tid >> 6, lane = tid & 63;
  int bn = blockIdx.x, bm = blockIdx.y;
  int brow = bm * BM, bcol = bn * BN;
  int wm = w >> 1, wn = w & 1;
  int fr = lane & 15, fg = lane >> 4;
  f32x4 acc[4][4];
  #pragma unroll
  for (int i = 0; i < 4; ++i)
    #pragma unroll
    for (int j = 0; j < 4; ++j) acc[i][j] = (f32x4){0.f, 0.f, 0.f, 0.f};

  constexpr int ACH = BM * BK / 8;
  constexpr int CALLS = (BM + BN) * BK / 8 / 64;

  for (int kt = 0; kt < K; kt += BK) {
    for (int j = 0; j * 4 + w < CALLS; ++j) {
      int cb = (j * 4 + w) * 64;
      int c = cb + lane;
      const u16* g;
      if (c < ACH) {
        int row = c >> 2, c8 = c & 3;
        g = A + (size_t)(brow + row) * K + kt + c8 * 8;
      } else {
        int b = c - ACH;
        int nn = b >> 2, c8 = b & 3;
        g = Bt + (size_t)(bcol + nn) * K + kt + c8 * 8;
      }
      gload16(g, &lds[cb * 8]);
    }
    asm volatile("s_waitcnt vmcnt(0)" ::: "memory");
    __syncthreads();

    const u16* Al = lds;
    const u16* Bl = lds + BM * BK;
    bf16x8 af[4], bfr[4];
    #pragma unroll
    for (int mi = 0; mi < 4; ++mi)
      af[mi] = *(const bf16x8*)&Al[(wm * 64 + mi * 16 + fr) * BK + fg * 8];
    #pragma unroll
    for (int ni = 0; ni < 4; ++ni)
      bfr[ni] = *(const bf16x8*)&Bl[(wn * 64 + ni * 16 + fr) * BK + fg * 8];
    #pragma unroll
    for (int mi = 0; mi < 4; ++mi)
      #pragma unroll
      for (int ni = 0; ni < 4; ++ni)
        acc[mi][ni] = __builtin_amdgcn_mfma_f32_16x16x32_bf16(af[mi], bfr[ni], acc[mi][ni], 0, 0, 0);
    __syncthreads();
  }

  #pragma unroll
  for (int ni = 0; ni < 4; ++ni) {
    int col = bcol + wn * 64 + ni * 16 + fr;
    float bb = bias[col];
    #pragma unroll
    for (int mi = 0; mi < 4; ++mi) {
      #pragma unroll
      for (int q = 0; q < 4; ++q) {
        int row = brow + wm * 64 + mi * 16 + fg * 4 + q;
        float vv = acc[mi][ni][q] + bb;
        C[(size_t)row * N + col] = f2bf(vv > 0.f ? vv : 0.f);
      }
    }
  }
}

// ------- GEMM3 fused with spline: BM=256, BN=192, BK=64, 8 waves, 4-phase counted-vmcnt -------
// Schedule identical to the R3 (922us) kernel. ONLY change: block->(bm,bn) map.
// L2-locality map: XCD x = bid&7 owns bn in [x*8, x*8+8) -> 8 B-panels = 3MB, L2-resident.
// Within an XCD, slots walk bn innermost (8 consecutive slots share one A-panel):
//   bm = bid>>6, bn = (bid&7)*8 + ((bid>>3)&7).   (bijective on 4096 blocks)
__global__ __launch_bounds__(512, 2)
void k_gemm3_fused(const u16* __restrict__ A, const u16* __restrict__ Bt,
                   const float* __restrict__ b2, const float* __restrict__ x2,
                   float* __restrict__ y2, float* __restrict__ ldpart) {
  extern __shared__ char smem[];
  const int tid = threadIdx.x, w = tid >> 6, lane = tid & 63;
  const int wm = w >> 2, wn = w & 3;
  const int fr = lane & 15, fg = lane >> 4;

  const int bid = blockIdx.x;
  const int bm = bid >> 6;
  const int bn = ((bid & 7) << 3) | ((bid >> 3) & 7);
  const int brow = bm * 256;

  // staging addresses: chunk c = tid within a unit: row_local = tid>>3, c8 = tid&7
  // source pre-swizzled: c8s = c8 ^ (row_local & 7); LDS dest linear (rule #21)
  const int csrc = (tid & 7) ^ ((tid >> 3) & 7);
  const u16* gA[4]; const u16* gB[3];
  int ldsA[4], ldsB[3];
  #pragma unroll
  for (int u = 0; u < 4; ++u) {
    gA[u] = A + (size_t)(brow + u * 64 + (tid >> 3)) * 1024 + csrc * 8;
    ldsA[u] = u * 8192 + tid * 16;
  }
  #pragma unroll
  for (int u = 0; u < 3; ++u) {
    gB[u] = Bt + (size_t)(bn * 192 + u * 64 + (tid >> 3)) * 1024 + csrc * 8;
    ldsB[u] = 65536 + u * 8192 + tid * 16;
  }

#define STG_A(u, t1) gload16(gA[u] + (size_t)(t1) * 64, smem + ldsA[u] + ((t1) & 1) * 32768)
#define STG_B(u, t1) gload16(gB[u] + (size_t)(t1) * 64, smem + ldsB[u] + ((t1) & 1) * 24576)
#define PHASE_BAR() { __builtin_amdgcn_sched_barrier(0); __builtin_amdgcn_s_barrier(); __builtin_amdgcn_sched_barrier(0); }

  // swizzled read chunk offsets (bytes): chunk = (kk*4+fg) ^ (row&7), row&7 == fr&7
  const int sc0 = ((fg ^ (fr & 7)) << 4);
  const int sc1 = (((4 + fg) ^ (fr & 7)) << 4);

#define RD_A(dst, mh, scv) {                                        \
    const char* ap_ = Ab + (wm * 128 + (mh) * 64 + fr) * 128 + (scv); \
    dst[0] = *(const bf16x8*)(ap_);                                 \
    dst[1] = *(const bf16x8*)(ap_ + 2048);                          \
    dst[2] = *(const bf16x8*)(ap_ + 4096);                          \
    dst[3] = *(const bf16x8*)(ap_ + 6144); }
#define RD_B(dst, scv) {                                            \
    const char* bp_ = Bb + (wn * 48 + fr) * 128 + (scv);            \
    dst[0] = *(const bf16x8*)(bp_);                                 \
    dst[1] = *(const bf16x8*)(bp_ + 2048);                          \
    dst[2] = *(const bf16x8*)(bp_ + 4096); }
#define MM(mh, af, bf) {                                            \
    __builtin_amdgcn_s_setprio(1);                                  \
    _Pragma("unroll")                                               \
    for (int i_ = 0; i_ < 4; ++i_)                                  \
      _Pragma("unroll")                                             \
      for (int n_ = 0; n_ < 3; ++n_)                                \
        acc[(mh) * 4 + i_][n_] = __builtin_amdgcn_mfma_f32_16x16x32_bf16(af[i_], bf[n_], acc[(mh) * 4 + i_][n_], 0, 0, 0); \
    __builtin_amdgcn_s_setprio(0); }

  f32x4 acc[8][3];
  #pragma unroll
  for (int m = 0; m < 8; ++m)
    #pragma unroll
    for (int n = 0; n < 3; ++n) acc[m][n] = (f32x4){0.f, 0.f, 0.f, 0.f};

  // prologue: tile 0 in deadline order, leave A1,A3 in flight
  STG_B(0, 0); STG_B(1, 0); STG_B(2, 0); STG_A(0, 0); STG_A(2, 0); STG_A(1, 0); STG_A(3, 0);
  asm volatile("s_waitcnt vmcnt(2)" ::: "memory");
  PHASE_BAR();

  for (int t = 0; t < 16; ++t) {
    const char* Ab = smem + (t & 1) * 32768;
    const char* Bb = smem + 65536 + (t & 1) * 24576;
    bf16x8 a[4], b0[3], b1[3];
    // ---- ph0: (mh0, kk0) ----
    if (t < 15) { STG_B(0, t + 1); STG_B(1, t + 1); }
    RD_B(b0, sc0);
    RD_A(a, 0, sc0);
    PHASE_BAR();
    MM(0, a, b0);
    // ---- ph1: (mh0, kk1) ----
    if (t < 15) { STG_B(2, t + 1); STG_A(0, t + 1); }
    RD_B(b1, sc1);
    RD_A(a, 0, sc1);
    if (t < 15) asm volatile("s_waitcnt vmcnt(4)" ::: "memory");
    else        asm volatile("s_waitcnt vmcnt(0)" ::: "memory");
    PHASE_BAR();
    MM(0, a, b1);
    // ---- ph2: (mh1, kk0) ----
    if (t < 15) { STG_A(2, t + 1); STG_A(1, t + 1); }
    RD_A(a, 1, sc0);
    PHASE_BAR();
    MM(1, a, b0);
    // ---- ph3: (mh1, kk1) ----
    if (t < 15) STG_A(3, t + 1);
    RD_A(a, 1, sc1);
    if (t < 15) asm volatile("s_waitcnt vmcnt(2)" ::: "memory");
    PHASE_BAR();
    MM(1, a, b1);
  }
  __syncthreads();

  // ---- epilogue: per-wave 128x48 p-subtile -> LDS slot -> spline (2 wm-rounds) ----
  float* ldaccs = (float*)(smem + 100352);  // [256][4]
  float* slot = (float*)smem + wn * (128 * 49);
  const int d2 = bn * 4 + wn;
  const float* bb = b2 + (size_t)d2 * 47;

  #pragma unroll
  for (int round = 0; round < 2; ++round) {
    if (wm == round) {
      #pragma unroll
      for (int m = 0; m < 8; ++m)
        #pragma unroll
        for (int n = 0; n < 3; ++n)
          #pragma unroll
          for (int q = 0; q < 4; ++q)
            slot[(m * 16 + fg * 4 + q) * 49 + n * 16 + fr] = acc[m][n][q];
      asm volatile("s_waitcnt lgkmcnt(0)" ::: "memory");
      #pragma unroll
      for (int rr = 0; rr < 2; ++rr) {
        int lr = rr * 64 + lane;
        int grow = brow + wm * 128 + lr;
        const float* pr = slot + lr * 49;

        float wv[16], hv[16];
        #pragma unroll
        for (int j = 0; j < 16; ++j) wv[j] = pr[j] + bb[j];
        #pragma unroll
        for (int j = 0; j < 16; ++j) hv[j] = pr[16 + j] + bb[16 + j];

        float x = x2[(size_t)grow * 256 + d2];
        float xc = fminf(fmaxf(x, -3.f), 3.f);

        float mw = wv[0];
        #pragma unroll
        for (int j = 1; j < 16; ++j) mw = fmaxf(mw, wv[j]);
        float sw = 0.f;
        #pragma unroll
        for (int j = 0; j < 16; ++j) { wv[j] = __expf(wv[j] - mw); sw += wv[j]; }
        float scw = 0.984f / sw;

        float mh = hv[0];
        #pragma unroll
        for (int j = 1; j < 16; ++j) mh = fmaxf(mh, hv[j]);
        float sh = 0.f;
        #pragma unroll
        for (int j = 0; j < 16; ++j) { hv[j] = __expf(hv[j] - mh); sh += hv[j]; }
        float sch = 0.984f / sh;

        int idx = 0;
        float xk = -3.f, cum = 0.f;
        #pragma unroll
        for (int i = 1; i <= 15; ++i) {
          cum += 0.001f + wv[i - 1] * scw;
          float cwi = 6.f * cum - 3.f;
          if (xc >= cwi) { idx = i; xk = cwi; }
        }
        float yk = -3.f, cumh = 0.f;
        #pragma unroll
        for (int i = 1; i <= 15; ++i) {
          cumh += 0.001f + hv[i - 1] * sch;
          float chi = 6.f * cumh - 3.f;
          if (i == idx) yk = chi;
        }
        float wk = 1.f, hk = 1.f;
        #pragma unroll
        for (int i = 0; i < 16; ++i) {
          if (i == idx) {
            wk = 6.f * (0.001f + wv[i] * scw);
            hk = 6.f * (0.001f + hv[i] * sch);
          }
        }
        float dk = 1.f, dk1 = 1.f;
        #pragma unroll
        for (int i = 1; i <= 15; ++i) {
          float u = pr[32 + i - 1] + bb[32 + i - 1];
          float e = __expf(u);
          float dd = 0.001f + (u > 15.f ? u : log1pf(e));
          if (i == idx) dk = dd;
          if (i == idx + 1) dk1 = dd;
        }

        float sk = hk / wk;
        float th = (xc - xk) / wk;
        float om = 1.f - th;
        float t1m = th * om;
        float den = sk + (dk + dk1 - 2.f * sk) * t1m;
        float y = yk + hk * (sk * th * th + dk * t1m) / den;
        float deriv = sk * sk * (dk1 * th * th + 2.f * sk * t1m + dk * om * om) / (den * den);
        bool inside = (x > -3.f) && (x < 3.f);
        float yout = inside ? y : x;
        float ld = inside ? __logf(deriv) : 0.f;

        y2[(size_t)grow * 256 + d2] = yout;
        ldaccs[(wm * 128 + lr) * 4 + wn] = ld;
      }
    }
    __syncthreads();
  }

  if (tid < 256) {
    int row = tid;
    float s = ldaccs[row * 4] + ldaccs[row * 4 + 1] + ldaccs[row * 4 + 2] + ldaccs[row * 4 + 3];
    ldpart[(size_t)bn * 16384 + brow + row] = s;
  }
}

__global__ void k_reduce_ld(const float* __restrict__ part, float* __restrict__ out) {
  int r = blockIdx.x * 256 + threadIdx.x;
  float s = 0.f;
  for (int j = 0; j < 64; ++j) s += part[(size_t)j * 16384 + r];
  out[r] = s;
}

// ---------------- launch ----------------
extern "C" void kernel_launch(void* const* d_in, const int* in_sizes, int n_in,
                              void* d_out, int out_size, void* d_ws, size_t ws_size,
                              hipStream_t stream) {
  const float* x1 = (const float*)d_in[0];
  const float* x2 = (const float*)d_in[1];
  const float* W0 = (const float*)d_in[2];
  const float* b0 = (const float*)d_in[3];
  const float* W1 = (const float*)d_in[4];
  const float* b1 = (const float*)d_in[5];
  const float* W2 = (const float*)d_in[6];
  const float* b2 = (const float*)d_in[7];
  float* y2 = (float*)d_out;
  float* logdet = y2 + (size_t)16384 * 256;

  char* ws = (char*)d_ws;
  u16* W2t = (u16*)ws;                                   // 25165824
  u16* W0t = (u16*)(ws + 25165824);                      //   524288
  u16* W1t = (u16*)(ws + 25165824 + 524288);             //  2097152
  u16* x1b = (u16*)(ws + 27787264);                      //  8388608
  float* ldp = (float*)(ws + 27787264);                  // aliases x1b (dead by GEMM3); 64*16384*4=4MB
  u16* h1  = (u16*)(ws + 36175872);                      // 33554432
  u16* h2  = (u16*)(ws + 69730304);                      // 33554432

  hipFuncSetAttribute((const void*)k_gemm3_fused,
                      hipFuncAttributeMaxDynamicSharedMemorySize, 114688);

  k_conv_bf16<<<16384, 256, 0, stream>>>(x1, x1b, 16384 * 256);
  k_transconv<<<dim3(8, 32), 256, 0, stream>>>(W0, W0t, 256, 1024, 1024, 0);
  k_transconv<<<dim3(32, 32), 256, 0, stream>>>(W1, W1t, 1024, 1024, 1024, 0);
  k_transconv<<<dim3(32, 384), 256, 0, stream>>>(W2, W2t, 1024, 12032, 12288, 1);

  k_gemm_relu<<<dim3(8, 128), 256, 0, stream>>>(x1b, W0t, b0, h1, 1024, 256);
  k_gemm_relu<<<dim3(8, 128), 256, 0, stream>>>(h1, W1t, b1, h2, 1024, 1024);
  k_gemm3_fused<<<4096, 512, 114688, stream>>>(h2, W2t, b2, x2, y2, ldp);
  k_reduce_ld<<<64, 256, 0, stream>>>(ldp, logdet);
}